// Round 4
// baseline (131.359 us; speedup 1.0000x reference)
//
#include <hip/hip_runtime.h>
#include <cstddef>
#include <cstdint>

#define NN 4096          // spatial n = 64*64
#define CIN 256          // input channels
#define CQKV 768         // qkv output channels
#define NBATCH 16
#define QSCALE 0.17677669529663687f  // 32^-0.5

typedef short s16x8 __attribute__((ext_vector_type(8)));
typedef float f32x4 __attribute__((ext_vector_type(4)));

__device__ __forceinline__ float bf2f(unsigned short u) {
    unsigned int x = ((unsigned int)u) << 16;
    return __builtin_bit_cast(float, x);
}
__device__ __forceinline__ unsigned short f2bf(float f) {
    unsigned int u = __builtin_bit_cast(unsigned int, f);
    return (unsigned short)((u + 0x7fffu + ((u >> 16) & 1u)) >> 16);   // RNE
}
__device__ __forceinline__ void glds16(const void* gsrc, void* lds) {
    __builtin_amdgcn_global_load_lds(
        (const __attribute__((address_space(1))) unsigned int*)gsrc,
        (__attribute__((address_space(3))) unsigned int*)lds,
        16, 0, 0);
}

// ---------------------------------------------------------------------------
// K0a: x [b][256][4096] f32  ->  xT [b][4096][256] bf16   (transpose + cast)
// ---------------------------------------------------------------------------
__global__ __launch_bounds__(256)
void xpose(const float* __restrict__ x, unsigned short* __restrict__ xT)
{
    const int b = blockIdx.z;
    const int n0 = blockIdx.x * 64, c0 = blockIdx.y * 64;
    __shared__ float xs[64][65];
    const int t = threadIdx.x;
    const float* xb = x + (size_t)b * CIN * NN;
#pragma unroll
    for (int p = 0; p < 4; ++p) {
        const int row = p * 16 + (t >> 4);
        const int col = (t & 15) * 4;
        const float4 v = *reinterpret_cast<const float4*>(
            &xb[(size_t)(c0 + row) * NN + n0 + col]);
        xs[col + 0][row] = v.x; xs[col + 1][row] = v.y;
        xs[col + 2][row] = v.z; xs[col + 3][row] = v.w;
    }
    __syncthreads();
    const int n = t >> 2, cch = (t & 3) * 16;
    unsigned short arr[16];
#pragma unroll
    for (int e = 0; e < 16; ++e) arr[e] = f2bf(xs[n][cch + e]);
    unsigned short* dst = xT + ((size_t)b * NN + n0 + n) * 256 + c0 + cch;
    *reinterpret_cast<s16x8*>(&dst[0]) = *reinterpret_cast<s16x8*>(&arr[0]);
    *reinterpret_cast<s16x8*>(&dst[8]) = *reinterpret_cast<s16x8*>(&arr[8]);
}

// K0b: w_qkv f32 -> bf16
__global__ __launch_bounds__(256)
void wcvt(const float* __restrict__ w, unsigned short* __restrict__ wb)
{
    const int i = (blockIdx.x * 256 + threadIdx.x) * 4;
    const float4 v = *reinterpret_cast<const float4*>(&w[i]);
    unsigned short a[4] = { f2bf(v.x), f2bf(v.y), f2bf(v.z), f2bf(v.w) };
    *reinterpret_cast<ushort2*>(&wb[i])     = *reinterpret_cast<ushort2*>(&a[0]);
    *reinterpret_cast<ushort2*>(&wb[i + 2]) = *reinterpret_cast<ushort2*>(&a[2]);
}

// ---------------------------------------------------------------------------
// BK=32 double-buffered 128x128 GEMM core for the fused kernel.
// A [128][256] bf16 row-major (pre-offset to m-tile), B = xT slab [128][256].
// LDS: A0/B0/A1/B1 at 0/8K/16K/24K. Chunk-XOR swizzle both sides.
// ---------------------------------------------------------------------------
__device__ __forceinline__ void gemm32(const unsigned short* __restrict__ Ab,
                                       const unsigned short* __restrict__ Bb,
                                       char* __restrict__ smem, f32x4 (&acc)[4][4])
{
    const int t = threadIdx.x;
    const int lane = t & 63, w = t >> 6;
    const int lr = lane & 15, lq = lane >> 4;
    const int wr = (w >> 1) * 64, wc = (w & 1) * 64;
    const int srow = t >> 2;                 // 0..63
    const int schunk = (t & 3) ^ (srow & 3); // pre-swizzled 16B chunk
    const int wq = w << 10;
    const int slot = (lq ^ (lr & 3)) << 4;   // read-side XOR slot
    char* A0 = smem;          char* B0 = smem + 8192;
    char* A1 = smem + 16384;  char* B1 = smem + 24576;

#define STG32(bufA, bufB, k0)                                                   \
    { glds16(Ab + (size_t)(srow) * 256 + (k0) + schunk * 8, (bufA) + wq);       \
      glds16(Ab + (size_t)(64 + srow) * 256 + (k0) + schunk * 8,                \
             (bufA) + 4096 + wq);                                               \
      glds16(Bb + (size_t)(srow) * 256 + (k0) + schunk * 8, (bufB) + wq);       \
      glds16(Bb + (size_t)(64 + srow) * 256 + (k0) + schunk * 8,                \
             (bufB) + 4096 + wq); }

#define CMP32(bufA, bufB)                                                       \
    { s16x8 af[4], bfr[4];                                                      \
      _Pragma("unroll") for (int m = 0; m < 4; ++m)                             \
        af[m] = *(const s16x8*)((bufA) + (wr + m * 16 + lr) * 64 + slot);       \
      _Pragma("unroll") for (int n = 0; n < 4; ++n)                             \
        bfr[n] = *(const s16x8*)((bufB) + (wc + n * 16 + lr) * 64 + slot);      \
      _Pragma("unroll") for (int m = 0; m < 4; ++m)                             \
      _Pragma("unroll") for (int n = 0; n < 4; ++n)                             \
        acc[m][n] = __builtin_amdgcn_mfma_f32_16x16x32_bf16(af[m], bfr[n],      \
                                                            acc[m][n], 0, 0, 0); }

    STG32(A0, B0, 0);   __syncthreads();
    STG32(A1, B1, 32);  CMP32(A0, B0); __syncthreads();
    STG32(A0, B0, 64);  CMP32(A1, B1); __syncthreads();
    STG32(A1, B1, 96);  CMP32(A0, B0); __syncthreads();
    STG32(A0, B0, 128); CMP32(A1, B1); __syncthreads();
    STG32(A1, B1, 160); CMP32(A0, B0); __syncthreads();
    STG32(A0, B0, 192); CMP32(A1, B1); __syncthreads();
    STG32(A1, B1, 224); CMP32(A0, B0); __syncthreads();
    CMP32(A1, B1);
#undef STG32
#undef CMP32
}

// ---------------------------------------------------------------------------
// Fused K1: per (batch, 128-col n-tile) block, compute all 6 m-tiles of
// qkv = w_qkv @ x:
//   q tiles  -> softmax over d (+SCALE) -> qT [b][n][256] bf16
//   k tiles  -> exp(acc) packed bf16 held in regs; Z partials -> z_part
//   v tiles  -> per-head LDS (swizzled) + ctx MFMA -> ctx_part partials
// k/v never touch HBM.
// ---------------------------------------------------------------------------
__global__ __launch_bounds__(256, 2)
void fused_qkv(const unsigned short* __restrict__ wb,
               const unsigned short* __restrict__ xT,
               unsigned short* __restrict__ qT,
               float* __restrict__ ctx_part,
               float* __restrict__ z_part)
{
    __shared__ __align__(16) char smem[49152];   // 32K staging | 8K ek | 8K v
    const int nt = blockIdx.x, b = blockIdx.y;
    const int n0 = nt * 128;
    const unsigned short* Bb = xT + ((size_t)b * NN + n0) * 256;
    const int t = threadIdx.x;
    const int lane = t & 63, w = t >> 6;
    const int lr = lane & 15, lq = lane >> 4;
    const int wr = (w >> 1) * 64, wc = (w & 1) * 64;

    f32x4 acc[4][4];
    unsigned int ekpk[4][4][2];   // packed exp(k) held across v-tile GEMM

    // ---------------- q tiles (m0 = 0, 128) ----------------
#pragma unroll
    for (int mq = 0; mq < 2; ++mq) {
#pragma unroll
        for (int m = 0; m < 4; ++m)
#pragma unroll
            for (int n = 0; n < 4; ++n) acc[m][n] = (f32x4){0.f, 0.f, 0.f, 0.f};
        gemm32(wb + (size_t)(mq * 128) * 256, Bb, smem, acc);
        __syncthreads();                         // staging free for scratch
        unsigned short (*qs)[136] = (unsigned short (*)[136])smem;
#pragma unroll
        for (int n = 0; n < 4; ++n) {
            const int col = wc + n * 16 + lr;
#pragma unroll
            for (int hp = 0; hp < 2; ++hp) {
                float mx = -1e30f;
#pragma unroll
                for (int u = 0; u < 2; ++u)
#pragma unroll
                    for (int r = 0; r < 4; ++r)
                        mx = fmaxf(mx, acc[hp * 2 + u][n][r]);
                mx = fmaxf(mx, __shfl_xor(mx, 16));
                mx = fmaxf(mx, __shfl_xor(mx, 32));
                float er[2][4];
                float s = 0.f;
#pragma unroll
                for (int u = 0; u < 2; ++u)
#pragma unroll
                    for (int r = 0; r < 4; ++r) {
                        er[u][r] = __expf(acc[hp * 2 + u][n][r] - mx);
                        s += er[u][r];
                    }
                s += __shfl_xor(s, 16);
                s += __shfl_xor(s, 32);
                const float inv = QSCALE / s;
#pragma unroll
                for (int u = 0; u < 2; ++u) {
                    ushort4 pk;
                    pk.x = f2bf(er[u][0] * inv);
                    pk.y = f2bf(er[u][1] * inv);
                    pk.z = f2bf(er[u][2] * inv);
                    pk.w = f2bf(er[u][3] * inv);
                    *(ushort4*)&qs[col][wr + (hp * 2 + u) * 16 + lq * 4] = pk;
                }
            }
        }
        __syncthreads();
        const int nl = t >> 1, half = t & 1;
        const unsigned short* src = &qs[nl][half * 64];
        unsigned short* dst = qT + ((size_t)b * NN + n0 + nl) * 256 + mq * 128 + half * 64;
#pragma unroll
        for (int i = 0; i < 8; ++i)
            *(s16x8*)(dst + i * 8) = *(const s16x8*)(src + i * 8);
        __syncthreads();
    }

    // ---------------- k/v groups ----------------
#pragma unroll
    for (int g = 0; g < 2; ++g) {
        // ---- k tile (rows 256 + g*128) ----
#pragma unroll
        for (int m = 0; m < 4; ++m)
#pragma unroll
            for (int n = 0; n < 4; ++n) acc[m][n] = (f32x4){0.f, 0.f, 0.f, 0.f};
        gemm32(wb + (size_t)(256 + g * 128) * 256, Bb, smem, acc);

        float zacc[4][4];
#pragma unroll
        for (int m = 0; m < 4; ++m)
#pragma unroll
            for (int r = 0; r < 4; ++r) zacc[m][r] = 0.f;
#pragma unroll
        for (int m = 0; m < 4; ++m)
#pragma unroll
            for (int n = 0; n < 4; ++n) {
                const unsigned short u0 = f2bf(__expf(acc[m][n][0]));
                const unsigned short u1 = f2bf(__expf(acc[m][n][1]));
                const unsigned short u2 = f2bf(__expf(acc[m][n][2]));
                const unsigned short u3 = f2bf(__expf(acc[m][n][3]));
                zacc[m][0] += bf2f(u0);   // Z from the ROUNDED values:
                zacc[m][1] += bf2f(u1);   // numerator/denominator consistent
                zacc[m][2] += bf2f(u2);
                zacc[m][3] += bf2f(u3);
                ekpk[m][n][0] = (unsigned int)u0 | ((unsigned int)u1 << 16);
                ekpk[m][n][1] = (unsigned int)u2 | ((unsigned int)u3 << 16);
            }
#pragma unroll
        for (int m = 0; m < 4; ++m)
#pragma unroll
            for (int r = 0; r < 4; ++r) {
                float z = zacc[m][r];
                z += __shfl_xor(z, 1);
                z += __shfl_xor(z, 2);
                z += __shfl_xor(z, 4);
                z += __shfl_xor(z, 8);
                if (lr == 0)
                    z_part[(((size_t)(b * 32 + nt)) * 2 + (wc >> 6)) * 256
                           + g * 128 + wr + m * 16 + lq * 4 + r] = z;
            }

        // ---- v tile (rows 512 + g*128) ----
#pragma unroll
        for (int m = 0; m < 4; ++m)
#pragma unroll
            for (int n = 0; n < 4; ++n) acc[m][n] = (f32x4){0.f, 0.f, 0.f, 0.f};
        gemm32(wb + (size_t)(512 + g * 128) * 256, Bb, smem, acc);

        // ---- per-head context: C[d][e] += sum_n ek[d][n] v[e][n] ----
#pragma unroll
        for (int hh = 0; hh < 4; ++hh) {
            if (wr == (hh >> 1) * 64) {       // 2 owner waves write LDS tiles
#pragma unroll
                for (int mi = 0; mi < 2; ++mi) {
                    const int m = ((hh & 1) << 1) + mi;
                    const int drow = mi * 16 + lq * 4;
#pragma unroll
                    for (int n = 0; n < 4; ++n) {
                        const int col = wc + n * 16 + lr;
#pragma unroll
                        for (int p = 0; p < 2; ++p) {
                            const unsigned int wd = ekpk[m][n][p];
                            const int d0 = drow + 2 * p, d1 = drow + 2 * p + 1;
                            *(unsigned short*)(smem + 32768 +
                                ((d0 * 256 + col * 2) ^ ((d0 & 7) << 4))) = (unsigned short)wd;
                            *(unsigned short*)(smem + 32768 +
                                ((d1 * 256 + col * 2) ^ ((d1 & 7) << 4))) = (unsigned short)(wd >> 16);
                        }
#pragma unroll
                        for (int r = 0; r < 4; ++r) {
                            const int e = drow + r;
                            *(unsigned short*)(smem + 40960 +
                                ((e * 256 + col * 2) ^ ((e & 7) << 4))) = f2bf(acc[m][n][r]);
                        }
                    }
                }
            }
            __syncthreads();
            const int fr = w >> 1, fc = w & 1;
            f32x4 ca = {};
#pragma unroll
            for (int kc = 0; kc < 4; ++kc) {
                const int ra = fr * 16 + lr, rb = fc * 16 + lr;
                const s16x8 av = *(const s16x8*)(smem + 32768 +
                    ((ra * 256 + kc * 64 + lq * 16) ^ ((ra & 7) << 4)));
                const s16x8 bv = *(const s16x8*)(smem + 40960 +
                    ((rb * 256 + kc * 64 + lq * 16) ^ ((rb & 7) << 4)));
                ca = __builtin_amdgcn_mfma_f32_16x16x32_bf16(av, bv, ca, 0, 0, 0);
            }
            float* cp = ctx_part + (((size_t)(b * 32 + nt)) * 8 + g * 4 + hh) * 1024
                        + (fr * 16 + lq * 4) * 32 + fc * 16 + lr;
#pragma unroll
            for (int r = 0; r < 4; ++r) cp[r * 32] = ca[r];
            __syncthreads();
        }
    }
}

// ---------------------------------------------------------------------------
// make_m: reduce 32 n-tile ctx partials + Z halves, fold w_out -> Mmat bf16
// ---------------------------------------------------------------------------
__global__ __launch_bounds__(256)
void make_m(const float* __restrict__ ctx_part, const float* __restrict__ z_part,
            const float* __restrict__ w_out, unsigned short* __restrict__ Mmat)
{
    const int h = blockIdx.x, b = blockIdx.y;
    const int t = threadIdx.x;
    __shared__ float ctx[32][33];
    __shared__ float zinv[32];

    for (int c = t; c < 1024; c += 256) {
        float s = 0.f;
#pragma unroll 8
        for (int nt = 0; nt < 32; ++nt)
            s += ctx_part[(((size_t)(b * 32 + nt)) * 8 + h) * 1024 + c];
        ctx[c >> 5][c & 31] = s;
    }
    if (t < 32) {
        float z = 0.f;
#pragma unroll 8
        for (int nt = 0; nt < 32; ++nt) {
            z += z_part[(((size_t)(b * 32 + nt)) * 2 + 0) * 256 + h * 32 + t];
            z += z_part[(((size_t)(b * 32 + nt)) * 2 + 1) * 256 + h * 32 + t];
        }
        zinv[t] = 1.f / z;
    }
    __syncthreads();

    const int o = t;
    float wrow[32];
#pragma unroll
    for (int e = 0; e < 32; ++e)
        wrow[e] = w_out[(size_t)o * 256 + h * 32 + e];
#pragma unroll 4
    for (int d = 0; d < 32; ++d) {
        float s = 0.f;
#pragma unroll
        for (int e = 0; e < 32; ++e)
            s = fmaf(wrow[e], ctx[d][e], s);
        Mmat[((size_t)b * 256 + o) * 256 + h * 32 + d] = f2bf(s * zinv[d]);
    }
}

// ---------------------------------------------------------------------------
// gemm_out: out = Mmat @ q + bias (f32), BK=64 double-buffered core (R2)
// ---------------------------------------------------------------------------
__device__ __forceinline__ void gemm_core64(const unsigned short* __restrict__ Ab,
                                            const unsigned short* __restrict__ Bb,
                                            int m0, int n0, char* smem,
                                            f32x4 (&acc)[4][4])
{
    const int t = threadIdx.x;
    const int lane = t & 63, w = t >> 6;
    const int lr = lane & 15, lq = lane >> 4;
    const int wr = (w >> 1) * 64, wc = (w & 1) * 64;
    const int srow = t >> 3;
    const int schunk = (t & 7) ^ (srow & 7);
    const int wq = w << 10;
    const int xr = lr & 7;

    char* A0 = smem;          char* B0 = smem + 16384;
    char* A1 = smem + 32768;  char* B1 = smem + 49152;

#define STG(bufA, bufB, k0)                                                     \
    { _Pragma("unroll") for (int i = 0; i < 4; ++i)                             \
        glds16(Ab + (size_t)(m0 + i*32 + srow)*256 + (k0) + schunk*8,           \
               (bufA) + i*4096 + wq);                                           \
      _Pragma("unroll") for (int i = 0; i < 4; ++i)                             \
        glds16(Bb + (size_t)(n0 + i*32 + srow)*256 + (k0) + schunk*8,           \
               (bufB) + i*4096 + wq); }

#define CMP(bufA, bufB)                                                         \
    { s16x8 af[4][2], bfr[4][2];                                                \
      _Pragma("unroll") for (int m = 0; m < 4; ++m) {                           \
        const char* rp = (bufA) + (wr + m*16 + lr)*128;                         \
        af[m][0] = *(const s16x8*)(rp + (((0*4 + lq) ^ xr) << 4));              \
        af[m][1] = *(const s16x8*)(rp + (((1*4 + lq) ^ xr) << 4)); }            \
      _Pragma("unroll") for (int n = 0; n < 4; ++n) {                           \
        const char* rp = (bufB) + (wc + n*16 + lr)*128;                         \
        bfr[n][0] = *(const s16x8*)(rp + (((0*4 + lq) ^ xr) << 4));             \
        bfr[n][1] = *(const s16x8*)(rp + (((1*4 + lq) ^ xr) << 4)); }           \
      _Pragma("unroll") for (int m = 0; m < 4; ++m)                             \
      _Pragma("unroll") for (int n = 0; n < 4; ++n) {                           \
        acc[m][n] = __builtin_amdgcn_mfma_f32_16x16x32_bf16(af[m][0], bfr[n][0], acc[m][n], 0, 0, 0); \
        acc[m][n] = __builtin_amdgcn_mfma_f32_16x16x32_bf16(af[m][1], bfr[n][1], acc[m][n], 0, 0, 0); }}

    STG(A0, B0, 0);
    __syncthreads();
    STG(A1, B1, 64);
    CMP(A0, B0);
    __syncthreads();
    STG(A0, B0, 128);
    CMP(A1, B1);
    __syncthreads();
    STG(A1, B1, 192);
    CMP(A0, B0);
    __syncthreads();
    CMP(A1, B1);
#undef STG
#undef CMP
}

__global__ __launch_bounds__(256, 2)
void gemm_out(const unsigned short* __restrict__ Mmat,
              const unsigned short* __restrict__ qT,
              float* __restrict__ out, const float* __restrict__ bias)
{
    __shared__ __align__(16) char smem[65536];
    const int bz = blockIdx.z;
    const int m0 = blockIdx.y * 128, n0 = blockIdx.x * 128;
    const unsigned short* Ab = Mmat + (size_t)bz * 256 * 256;
    const unsigned short* Bb = qT + (size_t)bz * NN * 256;

    f32x4 acc[4][4] = {};
    gemm_core64(Ab, Bb, m0, n0, smem, acc);

    const int t = threadIdx.x;
    const int lane = t & 63, w = t >> 6;
    const int lr = lane & 15, lq = lane >> 4;
    const int wr = (w >> 1) * 64, wc = (w & 1) * 64;

    float* Yb = out + (size_t)bz * CIN * NN;
#pragma unroll
    for (int m = 0; m < 4; ++m)
#pragma unroll
        for (int r = 0; r < 4; ++r) {
            const int row = m0 + wr + m * 16 + lq * 4 + r;
            const float bv = bias[row];
#pragma unroll
            for (int n = 0; n < 4; ++n)
                Yb[(size_t)row * NN + n0 + wc + n * 16 + lr] = acc[m][n][r] + bv;
        }
}

// ---------------------------------------------------------------------------
extern "C" void kernel_launch(void* const* d_in, const int* in_sizes, int n_in,
                              void* d_out, int out_size, void* d_ws, size_t ws_size,
                              hipStream_t stream)
{
    const float* x     = (const float*)d_in[0];
    const float* w_qkv = (const float*)d_in[1];
    const float* w_out = (const float*)d_in[2];
    const float* b_out = (const float*)d_in[3];
    float* out = (float*)d_out;

    char* ws = (char*)d_ws;
    size_t off = 0;
    unsigned short* xT  = (unsigned short*)(ws + off);  off += (size_t)NBATCH * NN * CIN * 2;      // 32 MiB
    unsigned short* qT  = (unsigned short*)(ws + off);  off += (size_t)NBATCH * NN * CIN * 2;      // 32 MiB
    float* ctx_part     = (float*)(ws + off);           off += (size_t)NBATCH * 32 * 8 * 1024 * 4; // 16 MiB
    float* z_part       = (float*)(ws + off);           off += (size_t)NBATCH * 32 * 2 * 256 * 4;  // 1 MiB
    unsigned short* Mmat= (unsigned short*)(ws + off);  off += (size_t)NBATCH * 256 * 256 * 2;     // 2 MiB
    unsigned short* wb  = (unsigned short*)(ws + off);  off += (size_t)CQKV * CIN * 2;

    // K0: transpose+cast x, cast w_qkv
    xpose<<<dim3(NN / 64, CIN / 64, NBATCH), 256, 0, stream>>>(x, xT);
    wcvt<<<dim3(CQKV * CIN / 1024), 256, 0, stream>>>(w_qkv, wb);

    // K1 (fused): qkv GEMM + q-softmax->qT + k-softmax-numerator + context partials
    fused_qkv<<<dim3(32, NBATCH), 256, 0, stream>>>(wb, xT, qT, ctx_part, z_part);

    // K4: Mmat = fold(w_out, normalized context)
    make_m<<<dim3(8, NBATCH), 256, 0, stream>>>(ctx_part, z_part, w_out, Mmat);

    // K5: out = Mmat @ q + b_out
    gemm_out<<<dim3(32, 2, NBATCH), 256, 0, stream>>>(Mmat, qT, out, b_out);
}